// Round 4
// baseline (564.320 us; speedup 1.0000x reference)
//
#include <hip/hip_runtime.h>
#include <cstdint>

#define M_DIM 8192
#define K_DIM 4096
#define N_DIM 12288
#define KTILES 64  // 64 K-tiles of BK=64 int8

using i32x4 = __attribute__((ext_vector_type(4))) int;
using i32x16 = __attribute__((ext_vector_type(16))) int;

__device__ inline void gload_lds16(const void* g, void* l) {
    __builtin_amdgcn_global_load_lds(
        (const __attribute__((address_space(1))) void*)g,
        (__attribute__((address_space(3))) void*)l,
        16, 0, 0);
}

// ---------------- fused: per-row quant (blocks 0..M-1) + weight repack ----------------
__global__ __launch_bounds__(256) void quant_pack(const float* __restrict__ x,
                                                  const int* __restrict__ w32,
                                                  int8_t* __restrict__ qa,
                                                  float* __restrict__ ascale,
                                                  int8_t* __restrict__ wq) {
    const int t = threadIdx.x;
    if (blockIdx.x < M_DIM) {
        const int row = blockIdx.x;
        const float4* xr = (const float4*)(x + (size_t)row * K_DIM);
        float4 v[4];
        float amax = 0.0f;
#pragma unroll
        for (int c = 0; c < 4; ++c) {
            v[c] = xr[t + 256 * c];
            amax = fmaxf(amax, fmaxf(fmaxf(fabsf(v[c].x), fabsf(v[c].y)),
                                     fmaxf(fabsf(v[c].z), fabsf(v[c].w))));
        }
#pragma unroll
        for (int off = 32; off > 0; off >>= 1)
            amax = fmaxf(amax, __shfl_xor(amax, off));
        __shared__ float smax[4];
        if ((t & 63) == 0) smax[t >> 6] = amax;
        __syncthreads();
        amax = fmaxf(fmaxf(smax[0], smax[1]), fmaxf(smax[2], smax[3]));
        const float sc = amax * (1.0f / 127.0f);
        const float inv = (amax > 0.0f) ? (127.0f / amax) : 0.0f;
        if (t == 0) ascale[row] = sc;

        int* q32 = (int*)(qa + (size_t)row * K_DIM);
#pragma unroll
        for (int c = 0; c < 4; ++c) {
            int q0 = (int)rintf(v[c].x * inv);
            int q1 = (int)rintf(v[c].y * inv);
            int q2 = (int)rintf(v[c].z * inv);
            int q3 = (int)rintf(v[c].w * inv);
            q0 = min(127, max(-128, q0));
            q1 = min(127, max(-128, q1));
            q2 = min(127, max(-128, q2));
            q3 = min(127, max(-128, q3));
            q32[t + 256 * c] = (q0 & 255) | ((q1 & 255) << 8) | ((q2 & 255) << 16) | (q3 << 24);
        }
    } else {
        const int pb = blockIdx.x - M_DIM;  // 0..2047
        const size_t total4 = (size_t)N_DIM * K_DIM / 4;
        const size_t stride = (size_t)2048 * 256;
        int* out32 = (int*)wq;
        for (size_t i = (size_t)pb * 256 + t; i < total4; i += stride) {
            const int4 v = ((const int4*)w32)[i];
            out32[i] = (v.x & 255) | ((v.y & 255) << 8) | ((v.z & 255) << 16) | (v.w << 24);
        }
    }
}

// ---------------- int8 GEMM, 256x256 tile, ring-4 LDS, counted vmcnt, 32x32x32 MFMA ----
__global__ __launch_bounds__(512, 2) void gemm_i8(const int8_t* __restrict__ qa,
                                                  const int8_t* __restrict__ wq,
                                                  const float* __restrict__ ascale,
                                                  const float* __restrict__ wscale,
                                                  const float* __restrict__ bias,
                                                  float* __restrict__ out) {
    __shared__ int8_t lds[4][2][256 * 64];  // ring of 4 K-tiles, 128 KiB

    const int t = threadIdx.x;
    const int lane = t & 63;
    const int wave = t >> 6;       // 0..7
    const int wm = wave >> 2;      // 0..1 -> 128 rows
    const int wn = wave & 3;       // 0..3 -> 64 cols
    const int l31 = lane & 31;
    const int lhi = lane >> 5;     // 0..1 -> 16B half of 32B k-chunk
    const int fr = (l31 >> 1) & 3; // read-side XOR swizzle (row-derived)

    // XCD-aware bijective swizzle: 1536 = 8 * 192
    const int flat = blockIdx.x;
    const int sw = (flat & 7) * 192 + (flat >> 3);
    const int bm = sw / 48;  // 0..31  (M tiles)
    const int bn = sw % 48;  // 0..47  (N tiles)

    // staging: per K-tile, A = 256 rows x 4 slots of 16B (linear), B same.
    // thread t covers slots s = t and s = t+512; row = s>>2, sl = s&3.
    // global k-slot = sl ^ ((row>>1)&3)  (same involution the reader uses).
    const int row0 = t >> 2;                    // 0..127 (second row = +128, same swz)
    const int g = (t & 3) ^ ((t >> 3) & 3);     // (t&3) ^ ((row0>>1)&3)
    const size_t aoff0 = (size_t)(bm * 256 + row0) * K_DIM + (size_t)g * 16;
    const size_t aoff1 = aoff0 + (size_t)128 * K_DIM;
    const size_t boff0 = (size_t)(bn * 256 + row0) * K_DIM + (size_t)g * 16;
    const size_t boff1 = boff0 + (size_t)128 * K_DIM;

    i32x16 acc[4][2] = {};

    // prologue: stage K-tiles 0 and 1 (8 loads/thread in flight)
#pragma unroll
    for (int p = 0; p < 2; ++p) {
        const size_t ko = (size_t)p * 64;
        gload_lds16(qa + aoff0 + ko, &lds[p][0][t * 16]);
        gload_lds16(qa + aoff1 + ko, &lds[p][0][t * 16 + 8192]);
        gload_lds16(wq + boff0 + ko, &lds[p][1][t * 16]);
        gload_lds16(wq + boff1 + ko, &lds[p][1][t * 16 + 8192]);
    }

    for (int j = 0; j < KTILES; ++j) {
        const int cb = j & 3;
        if (j + 2 < KTILES) {
            const int sb = (j + 2) & 3;
            const size_t ko = (size_t)(j + 2) * 64;
            gload_lds16(qa + aoff0 + ko, &lds[sb][0][t * 16]);
            gload_lds16(qa + aoff1 + ko, &lds[sb][0][t * 16 + 8192]);
            gload_lds16(wq + boff0 + ko, &lds[sb][1][t * 16]);
            gload_lds16(wq + boff1 + ko, &lds[sb][1][t * 16 + 8192]);
            asm volatile("s_waitcnt vmcnt(8)" ::: "memory");  // tile j landed
        } else if (j + 1 < KTILES) {
            asm volatile("s_waitcnt vmcnt(4)" ::: "memory");
        } else {
            asm volatile("s_waitcnt vmcnt(0)" ::: "memory");
        }
        __builtin_amdgcn_s_barrier();
        __builtin_amdgcn_sched_barrier(0);

        const int8_t* __restrict__ LA = lds[cb][0];
        const int8_t* __restrict__ LB = lds[cb][1];
        i32x4 af[2][4], bf[2][2];
#pragma unroll
        for (int ks = 0; ks < 2; ++ks) {
#pragma unroll
            for (int mf = 0; mf < 4; ++mf) {
                const int r = wm * 128 + mf * 32 + l31;
                const int slot = (ks * 2 + lhi) ^ fr;
                af[ks][mf] = *(const i32x4*)&LA[r * 64 + (slot << 4)];
            }
#pragma unroll
            for (int nf = 0; nf < 2; ++nf) {
                const int r = wn * 64 + nf * 32 + l31;
                const int slot = (ks * 2 + lhi) ^ fr;
                bf[ks][nf] = *(const i32x4*)&LB[r * 64 + (slot << 4)];
            }
        }
        __builtin_amdgcn_s_setprio(1);
#pragma unroll
        for (int ks = 0; ks < 2; ++ks)
#pragma unroll
            for (int mf = 0; mf < 4; ++mf)
#pragma unroll
                for (int nf = 0; nf < 2; ++nf)
                    acc[mf][nf] = __builtin_amdgcn_mfma_i32_32x32x32_i8(
                        af[ks][mf], bf[ks][nf], acc[mf][nf], 0, 0, 0);
        __builtin_amdgcn_s_setprio(0);
    }

    // epilogue: 32x32 C/D layout: col = lane&31, row = (reg&3)+8*(reg>>2)+4*(lane>>5)
    const int r0 = bm * 256 + wm * 128;
    const int c0 = bn * 256 + wn * 64;
#pragma unroll
    for (int mf = 0; mf < 4; ++mf) {
        float a16[16];
#pragma unroll
        for (int reg = 0; reg < 16; ++reg) {
            const int rif = (reg & 3) + 8 * (reg >> 2) + 4 * lhi;
            a16[reg] = ascale[r0 + mf * 32 + rif];
        }
#pragma unroll
        for (int nf = 0; nf < 2; ++nf) {
            const int col = c0 + nf * 32 + l31;
            const float wsc = wscale[col];
            const float bb = bias[col];
#pragma unroll
            for (int reg = 0; reg < 16; ++reg) {
                const int rif = (reg & 3) + 8 * (reg >> 2) + 4 * lhi;
                const int row = r0 + mf * 32 + rif;
                out[(size_t)row * N_DIM + col] = (float)acc[mf][nf][reg] * a16[reg] * wsc + bb;
            }
        }
    }
}

extern "C" void kernel_launch(void* const* d_in, const int* in_sizes, int n_in,
                              void* d_out, int out_size, void* d_ws, size_t ws_size,
                              hipStream_t stream) {
    const float* x = (const float*)d_in[0];
    const int* w32 = (const int*)d_in[1];  // int8 weights arrive as int32
    const float* wscale = (const float*)d_in[2];
    const float* bias = (const float*)d_in[3];
    float* out = (float*)d_out;

    int8_t* qa = (int8_t*)d_ws;                                     // M*K int8
    float* ascale = (float*)((char*)d_ws + (size_t)M_DIM * K_DIM);  // M f32
    int8_t* wq = (int8_t*)((char*)d_ws + (size_t)M_DIM * K_DIM +
                           (size_t)M_DIM * sizeof(float));          // N*K int8

    quant_pack<<<M_DIM + 2048, 256, 0, stream>>>(x, w32, qa, ascale, wq);
    gemm_i8<<<1536, 512, 0, stream>>>(qa, wq, ascale, wscale, bias, out);
}

// Round 5
// 555.340 us; speedup vs baseline: 1.0162x; 1.0162x over previous
//
#include <hip/hip_runtime.h>
#include <cstdint>

#define M_DIM 8192
#define K_DIM 4096
#define N_DIM 12288
#define KT 64  // K-tiles of BK=64 int8 (64 B per row)

using i32x4 = __attribute__((ext_vector_type(4))) int;

__device__ inline void gload_lds16(const void* g, void* l) {
    __builtin_amdgcn_global_load_lds(
        (const __attribute__((address_space(1))) void*)g,
        (__attribute__((address_space(3))) void*)l,
        16, 0, 0);
}

// ---------------- fused: per-row quant (blocks 0..M-1) + weight repack ----------------
__global__ __launch_bounds__(256) void quant_pack(const float* __restrict__ x,
                                                  const int* __restrict__ w32,
                                                  int8_t* __restrict__ qa,
                                                  float* __restrict__ ascale,
                                                  int8_t* __restrict__ wq) {
    const int t = threadIdx.x;
    if (blockIdx.x < M_DIM) {
        const int row = blockIdx.x;
        const float4* xr = (const float4*)(x + (size_t)row * K_DIM);
        float4 v[4];
        float amax = 0.0f;
#pragma unroll
        for (int c = 0; c < 4; ++c) {
            v[c] = xr[t + 256 * c];
            amax = fmaxf(amax, fmaxf(fmaxf(fabsf(v[c].x), fabsf(v[c].y)),
                                     fmaxf(fabsf(v[c].z), fabsf(v[c].w))));
        }
#pragma unroll
        for (int off = 32; off > 0; off >>= 1)
            amax = fmaxf(amax, __shfl_xor(amax, off));
        __shared__ float smax[4];
        if ((t & 63) == 0) smax[t >> 6] = amax;
        __syncthreads();
        amax = fmaxf(fmaxf(smax[0], smax[1]), fmaxf(smax[2], smax[3]));
        const float sc = amax * (1.0f / 127.0f);
        const float inv = (amax > 0.0f) ? (127.0f / amax) : 0.0f;
        if (t == 0) ascale[row] = sc;

        int* q32 = (int*)(qa + (size_t)row * K_DIM);
#pragma unroll
        for (int c = 0; c < 4; ++c) {
            int q0 = (int)rintf(v[c].x * inv);
            int q1 = (int)rintf(v[c].y * inv);
            int q2 = (int)rintf(v[c].z * inv);
            int q3 = (int)rintf(v[c].w * inv);
            q0 = min(127, max(-128, q0));
            q1 = min(127, max(-128, q1));
            q2 = min(127, max(-128, q2));
            q3 = min(127, max(-128, q3));
            q32[t + 256 * c] = (q0 & 255) | ((q1 & 255) << 8) | ((q2 & 255) << 16) | (q3 << 24);
        }
    } else {
        const int pb = blockIdx.x - M_DIM;  // 0..2047
        const size_t total4 = (size_t)N_DIM * K_DIM / 4;
        const size_t stride = (size_t)2048 * 256;
        int* out32 = (int*)wq;
        for (size_t i = (size_t)pb * 256 + t; i < total4; i += stride) {
            const int4 v = ((const int4*)w32)[i];
            out32[i] = (v.x & 255) | ((v.y & 255) << 8) | ((v.z & 255) << 16) | (v.w << 24);
        }
    }
}

// ---------------- int8 GEMM: 256x256 tile, ring-4, 2-phase/K-tile 8-phase cadence ----
__global__ __launch_bounds__(512, 2) void gemm_i8(const int8_t* __restrict__ qa,
                                                  const int8_t* __restrict__ wq,
                                                  const float* __restrict__ ascale,
                                                  const float* __restrict__ wscale,
                                                  const float* __restrict__ bias,
                                                  float* __restrict__ out) {
    // ring of 4 K-tile slots; each slot: A[256][64] + B[256][64] int8 = 32 KB
    __shared__ int8_t lds[4][2][16384];  // 128 KiB

    const int t = threadIdx.x;
    const int lane = t & 63;
    const int wave = t >> 6;       // 0..7
    const int wm = wave >> 2;      // 0..1 -> 128 rows of A
    const int wn = wave & 3;       // 0..3 -> 64 rows of B (cols of C)
    const int lrow = lane & 15;
    const int lk = lane >> 4;      // 0..3 (16B k-slot)
    const int rslot = (lk ^ ((lrow >> 1) & 3)) << 4;  // swizzled slot byte-offset

    // XCD-aware bijective swizzle: 1536 = 8 * 192
    const int flat = blockIdx.x;
    const int sw = (flat & 7) * 192 + (flat >> 3);
    const int bm = sw / 48;  // 0..31
    const int bn = sw % 48;  // 0..47

    // staging: per operand per K-tile = 16 KB = 1024 x 16B slots; thread t covers
    // linear slots t and t+512. row = slot>>2, sl = slot&3; global k-slot =
    // sl ^ ((row>>1)&3) (same involution the reader uses; LDS dest stays linear).
    const int g = (t & 3) ^ ((t >> 3) & 3);
    const size_t aoff0 = (size_t)(bm * 256 + (t >> 2)) * K_DIM + (size_t)g * 16;
    const size_t aoff1 = aoff0 + (size_t)128 * K_DIM;
    const size_t boff0 = (size_t)(bn * 256 + (t >> 2)) * K_DIM + (size_t)g * 16;
    const size_t boff1 = boff0 + (size_t)128 * K_DIM;

#define STAGE_A(sb, jt)                                                      \
    {                                                                        \
        gload_lds16(qa + aoff0 + (size_t)(jt) * 64, &lds[sb][0][t * 16]);    \
        gload_lds16(qa + aoff1 + (size_t)(jt) * 64,                          \
                    &lds[sb][0][t * 16 + 8192]);                             \
    }
#define STAGE_B(sb, jt)                                                      \
    {                                                                        \
        gload_lds16(wq + boff0 + (size_t)(jt) * 64, &lds[sb][1][t * 16]);    \
        gload_lds16(wq + boff1 + (size_t)(jt) * 64,                          \
                    &lds[sb][1][t * 16 + 8192]);                             \
    }

    i32x4 acc[8][4] = {};

    // prologue: stage tiles 0,1,2 (12 wave-loads outstanding, oldest-first)
#pragma unroll
    for (int p = 0; p < 3; ++p) {
        STAGE_A(p, p);
        STAGE_B(p, p);
    }

    for (int j = 0; j < KT; ++j) {
        const int cb = j & 3;
        const int pb = (j + 3) & 3;

        // ---- phase 0: stage A(j+3) | wait tile j | bf + af(0..3) | 16 MFMA ----
        if (j + 3 < KT) {
            STAGE_A(pb, j + 3);
            // outstanding: tiles j+1 (4) + j+2 (4) + just-issued 2 = 10
            asm volatile("s_waitcnt vmcnt(10)" ::: "memory");
        } else if (j + 2 < KT) {
            asm volatile("s_waitcnt vmcnt(8)" ::: "memory");
        } else if (j + 1 < KT) {
            asm volatile("s_waitcnt vmcnt(4)" ::: "memory");
        } else {
            asm volatile("s_waitcnt vmcnt(0)" ::: "memory");
        }
        __builtin_amdgcn_s_barrier();  // tile j landed for ALL waves
        __builtin_amdgcn_sched_barrier(0);

        const int8_t* __restrict__ LA = lds[cb][0];
        const int8_t* __restrict__ LB = lds[cb][1];
        i32x4 af[4], bf[4], ah[4];
#pragma unroll
        for (int nf = 0; nf < 4; ++nf)
            bf[nf] = *(const i32x4*)&LB[(wn * 64 + nf * 16 + lrow) * 64 + rslot];
#pragma unroll
        for (int mf = 0; mf < 4; ++mf)
            af[mf] = *(const i32x4*)&LA[(wm * 128 + mf * 16 + lrow) * 64 + rslot];
        asm volatile("s_waitcnt lgkmcnt(0)" ::: "memory");
        __builtin_amdgcn_sched_barrier(0);
        __builtin_amdgcn_s_setprio(1);
#pragma unroll
        for (int mf = 0; mf < 4; ++mf)
#pragma unroll
            for (int nf = 0; nf < 4; ++nf)
                acc[mf][nf] = __builtin_amdgcn_mfma_i32_16x16x64_i8(
                    af[mf], bf[nf], acc[mf][nf], 0, 0, 0);
        __builtin_amdgcn_s_setprio(0);
        __builtin_amdgcn_s_barrier();

        // ---- phase 1: af(4..7) | stage B(j+3) | 16 MFMA ----
#pragma unroll
        for (int mf = 0; mf < 4; ++mf)
            ah[mf] = *(const i32x4*)&LA[(wm * 128 + (mf + 4) * 16 + lrow) * 64 + rslot];
        if (j + 3 < KT) STAGE_B(pb, j + 3);
        __builtin_amdgcn_s_barrier();
        asm volatile("s_waitcnt lgkmcnt(0)" ::: "memory");
        __builtin_amdgcn_sched_barrier(0);
        __builtin_amdgcn_s_setprio(1);
#pragma unroll
        for (int mf = 0; mf < 4; ++mf)
#pragma unroll
            for (int nf = 0; nf < 4; ++nf)
                acc[mf + 4][nf] = __builtin_amdgcn_mfma_i32_16x16x64_i8(
                    ah[mf], bf[nf], acc[mf + 4][nf], 0, 0, 0);
        __builtin_amdgcn_s_setprio(0);
        __builtin_amdgcn_s_barrier();
    }

    // epilogue: C/D layout col = lane&15, row = (lane>>4)*4 + j
    const int r0 = bm * 256 + wm * 128;
    const int c0 = bn * 256 + wn * 64;
    float asc[8][4];
#pragma unroll
    for (int m = 0; m < 8; ++m)
#pragma unroll
        for (int jj = 0; jj < 4; ++jj)
            asc[m][jj] = ascale[r0 + m * 16 + lk * 4 + jj];
#pragma unroll
    for (int n = 0; n < 4; ++n) {
        const int col = c0 + n * 16 + lrow;
        const float wsc = wscale[col];
        const float bb = bias[col];
#pragma unroll
        for (int m = 0; m < 8; ++m) {
#pragma unroll
            for (int jj = 0; jj < 4; ++jj) {
                const int row = r0 + m * 16 + lk * 4 + jj;
                out[(size_t)row * N_DIM + col] = (float)acc[m][n][jj] * asc[m][jj] * wsc + bb;
            }
        }
    }
}

extern "C" void kernel_launch(void* const* d_in, const int* in_sizes, int n_in,
                              void* d_out, int out_size, void* d_ws, size_t ws_size,
                              hipStream_t stream) {
    const float* x = (const float*)d_in[0];
    const int* w32 = (const int*)d_in[1];  // int8 weights arrive as int32
    const float* wscale = (const float*)d_in[2];
    const float* bias = (const float*)d_in[3];
    float* out = (float*)d_out;

    int8_t* qa = (int8_t*)d_ws;                                     // M*K int8
    float* ascale = (float*)((char*)d_ws + (size_t)M_DIM * K_DIM);  // M f32
    int8_t* wq = (int8_t*)((char*)d_ws + (size_t)M_DIM * K_DIM +
                           (size_t)M_DIM * sizeof(float));          // N*K int8

    quant_pack<<<M_DIM + 2048, 256, 0, stream>>>(x, w32, qa, ascale, wq);
    gemm_i8<<<1536, 512, 0, stream>>>(qa, wq, ascale, wscale, bias, out);
}

// Round 6
// 543.184 us; speedup vs baseline: 1.0389x; 1.0224x over previous
//
#include <hip/hip_runtime.h>
#include <cstdint>

#define M_DIM 8192
#define K_DIM 4096
#define N_DIM 12288
#define KT 64  // K-tiles of BK=64 int8 (64 B per row)

using i32x4 = __attribute__((ext_vector_type(4))) int;

__device__ inline void gload_lds16(const void* g, void* l) {
    __builtin_amdgcn_global_load_lds(
        (const __attribute__((address_space(1))) void*)g,
        (__attribute__((address_space(3))) void*)l,
        16, 0, 0);
}

// ---------------- fused: per-row quant (blocks 0..M-1) + weight repack ----------------
__global__ __launch_bounds__(256) void quant_pack(const float* __restrict__ x,
                                                  const int* __restrict__ w32,
                                                  int8_t* __restrict__ qa,
                                                  float* __restrict__ ascale,
                                                  int8_t* __restrict__ wq) {
    const int t = threadIdx.x;
    if (blockIdx.x < M_DIM) {
        const int row = blockIdx.x;
        const float4* xr = (const float4*)(x + (size_t)row * K_DIM);
        float4 v[4];
        float amax = 0.0f;
#pragma unroll
        for (int c = 0; c < 4; ++c) {
            v[c] = xr[t + 256 * c];
            amax = fmaxf(amax, fmaxf(fmaxf(fabsf(v[c].x), fabsf(v[c].y)),
                                     fmaxf(fabsf(v[c].z), fabsf(v[c].w))));
        }
#pragma unroll
        for (int off = 32; off > 0; off >>= 1)
            amax = fmaxf(amax, __shfl_xor(amax, off));
        __shared__ float smax[4];
        if ((t & 63) == 0) smax[t >> 6] = amax;
        __syncthreads();
        amax = fmaxf(fmaxf(smax[0], smax[1]), fmaxf(smax[2], smax[3]));
        const float sc = amax * (1.0f / 127.0f);
        const float inv = (amax > 0.0f) ? (127.0f / amax) : 0.0f;
        if (t == 0) ascale[row] = sc;

        int* q32 = (int*)(qa + (size_t)row * K_DIM);
#pragma unroll
        for (int c = 0; c < 4; ++c) {
            int q0 = (int)rintf(v[c].x * inv);
            int q1 = (int)rintf(v[c].y * inv);
            int q2 = (int)rintf(v[c].z * inv);
            int q3 = (int)rintf(v[c].w * inv);
            q0 = min(127, max(-128, q0));
            q1 = min(127, max(-128, q1));
            q2 = min(127, max(-128, q2));
            q3 = min(127, max(-128, q3));
            q32[t + 256 * c] = (q0 & 255) | ((q1 & 255) << 8) | ((q2 & 255) << 16) | (q3 << 24);
        }
    } else {
        const int pb = blockIdx.x - M_DIM;  // 0..2047
        const size_t total4 = (size_t)N_DIM * K_DIM / 4;
        const size_t stride = (size_t)2048 * 256;
        int* out32 = (int*)wq;
        for (size_t i = (size_t)pb * 256 + t; i < total4; i += stride) {
            const int4 v = ((const int4*)w32)[i];
            out32[i] = (v.x & 255) | ((v.y & 255) << 8) | ((v.z & 255) << 16) | (v.w << 24);
        }
    }
}

// ---- int8 GEMM: 256x256 tile, ring-4 LDS, counted vmcnt, reg-double-buffered frags ----
__global__ __launch_bounds__(512, 2) void gemm_i8(const int8_t* __restrict__ qa,
                                                  const int8_t* __restrict__ wq,
                                                  const float* __restrict__ ascale,
                                                  const float* __restrict__ wscale,
                                                  const float* __restrict__ bias,
                                                  float* __restrict__ out) {
    __shared__ int8_t lds[4][2][16384];  // ring of 4 K-tile slots, 128 KiB

    const int t = threadIdx.x;
    const int lane = t & 63;
    const int wave = t >> 6;       // 0..7
    const int wm = wave >> 2;      // 0..1 -> 128 rows of A
    const int wn = wave & 3;       // 0..3 -> 64 rows of B (cols of C)
    const int lrow = lane & 15;
    const int lk = lane >> 4;      // 0..3 (16B k-slot)
    const int rslot = (lk ^ ((lrow >> 1) & 3)) << 4;  // conflict-free (r5: 0 conflicts)

    // XCD-aware bijective swizzle: 1536 = 8 * 192
    const int flat = blockIdx.x;
    const int sw = (flat & 7) * 192 + (flat >> 3);
    const int bm = sw / 48;  // 0..31
    const int bn = sw % 48;  // 0..47

    // staging: linear LDS dest; swizzle via permuted GLOBAL k-slot (same involution
    // the reader uses). thread t covers linear 16B slots t and t+512 per operand.
    const int g = (t & 3) ^ ((t >> 3) & 3);
    const size_t aoff0 = (size_t)(bm * 256 + (t >> 2)) * K_DIM + (size_t)g * 16;
    const size_t aoff1 = aoff0 + (size_t)128 * K_DIM;
    const size_t boff0 = (size_t)(bn * 256 + (t >> 2)) * K_DIM + (size_t)g * 16;
    const size_t boff1 = boff0 + (size_t)128 * K_DIM;

#define STAGE_ALL(sb, jt)                                                     \
    {                                                                         \
        gload_lds16(qa + aoff0 + (size_t)(jt) * 64, &lds[sb][0][t * 16]);     \
        gload_lds16(qa + aoff1 + (size_t)(jt) * 64, &lds[sb][0][t * 16 + 8192]); \
        gload_lds16(wq + boff0 + (size_t)(jt) * 64, &lds[sb][1][t * 16]);     \
        gload_lds16(wq + boff1 + (size_t)(jt) * 64, &lds[sb][1][t * 16 + 8192]); \
    }

    i32x4 acc[8][4] = {};
    i32x4 fa0[8], fb0[4], fa1[8], fb1[4];

    // prologue: stage tiles 0,1,2 (12 loads/wave outstanding, oldest first)
#pragma unroll
    for (int p = 0; p < 3; ++p) STAGE_ALL(p, p);
    asm volatile("s_waitcnt vmcnt(8)" ::: "memory");  // tile 0 landed (own slice)
    __builtin_amdgcn_s_barrier();                     // ...for all waves
    __builtin_amdgcn_sched_barrier(0);
    {
        const int8_t* __restrict__ LA = lds[0][0];
        const int8_t* __restrict__ LB = lds[0][1];
#pragma unroll
        for (int nf = 0; nf < 4; ++nf)
            fb0[nf] = *(const i32x4*)&LB[(wn * 64 + nf * 16 + lrow) * 64 + rslot];
#pragma unroll
        for (int mf = 0; mf < 8; ++mf)
            fa0[mf] = *(const i32x4*)&LA[(wm * 128 + mf * 16 + lrow) * 64 + rslot];
    }

    // per-iter: STAGE(j+3) | wait tile j+1 | barrier | ds_read frags(j+1) into NEXT
    //           | 32 MFMA of tile j from CUR | lgkmcnt(0)
    // Slot-reuse race: reads of slot s=(j+1)&3 retire before barrier(j+1) [the
    // end-of-iter lgkmcnt(0)]; the DMA that overwrites s (tile j+5) is issued
    // after barrier(j+2). Two barriers apart -> race-free.
#define ITER(J, CA, CB, NA, NB)                                               \
    do {                                                                      \
        if ((J) + 3 < KT) {                                                   \
            STAGE_ALL(((J) + 3) & 3, (J) + 3);                                \
            asm volatile("s_waitcnt vmcnt(8)" ::: "memory");                  \
        } else if ((J) + 2 < KT) {                                            \
            asm volatile("s_waitcnt vmcnt(4)" ::: "memory");                  \
        } else if ((J) + 1 < KT) {                                            \
            asm volatile("s_waitcnt vmcnt(0)" ::: "memory");                  \
        }                                                                     \
        __builtin_amdgcn_s_barrier();                                         \
        __builtin_amdgcn_sched_barrier(0);                                    \
        if ((J) + 1 < KT) {                                                   \
            const int8_t* __restrict__ LA = lds[((J) + 1) & 3][0];            \
            const int8_t* __restrict__ LB = lds[((J) + 1) & 3][1];            \
            _Pragma("unroll")                                                 \
            for (int nf = 0; nf < 4; ++nf)                                    \
                NB[nf] = *(const i32x4*)&LB[(wn * 64 + nf * 16 + lrow) * 64 + rslot]; \
            _Pragma("unroll")                                                 \
            for (int mf = 0; mf < 8; ++mf)                                    \
                NA[mf] = *(const i32x4*)&LA[(wm * 128 + mf * 16 + lrow) * 64 + rslot]; \
        }                                                                     \
        __builtin_amdgcn_sched_barrier(0);                                    \
        __builtin_amdgcn_s_setprio(1);                                        \
        _Pragma("unroll")                                                     \
        for (int mf = 0; mf < 8; ++mf)                                        \
            _Pragma("unroll")                                                 \
            for (int nf = 0; nf < 4; ++nf)                                    \
                acc[mf][nf] = __builtin_amdgcn_mfma_i32_16x16x64_i8(          \
                    CA[mf], CB[nf], acc[mf][nf], 0, 0, 0);                    \
        __builtin_amdgcn_s_setprio(0);                                        \
        asm volatile("s_waitcnt lgkmcnt(0)" ::: "memory");                    \
        __builtin_amdgcn_sched_barrier(0);                                    \
    } while (0)

    for (int j = 0; j < KT; j += 2) {
        ITER(j, fa0, fb0, fa1, fb1);
        ITER(j + 1, fa1, fb1, fa0, fb0);
    }

    // epilogue: C/D layout col = lane&15, row = (lane>>4)*4 + j
    const int r0 = bm * 256 + wm * 128;
    const int c0 = bn * 256 + wn * 64;
    float asc[8][4];
#pragma unroll
    for (int m = 0; m < 8; ++m)
#pragma unroll
        for (int jj = 0; jj < 4; ++jj)
            asc[m][jj] = ascale[r0 + m * 16 + lk * 4 + jj];
#pragma unroll
    for (int n = 0; n < 4; ++n) {
        const int col = c0 + n * 16 + lrow;
        const float wsc = wscale[col];
        const float bb = bias[col];
#pragma unroll
        for (int m = 0; m < 8; ++m) {
#pragma unroll
            for (int jj = 0; jj < 4; ++jj) {
                const int row = r0 + m * 16 + lk * 4 + jj;
                out[(size_t)row * N_DIM + col] = (float)acc[m][n][jj] * asc[m][jj] * wsc + bb;
            }
        }
    }
}

extern "C" void kernel_launch(void* const* d_in, const int* in_sizes, int n_in,
                              void* d_out, int out_size, void* d_ws, size_t ws_size,
                              hipStream_t stream) {
    const float* x = (const float*)d_in[0];
    const int* w32 = (const int*)d_in[1];  // int8 weights arrive as int32
    const float* wscale = (const float*)d_in[2];
    const float* bias = (const float*)d_in[3];
    float* out = (float*)d_out;

    int8_t* qa = (int8_t*)d_ws;                                     // M*K int8
    float* ascale = (float*)((char*)d_ws + (size_t)M_DIM * K_DIM);  // M f32
    int8_t* wq = (int8_t*)((char*)d_ws + (size_t)M_DIM * K_DIM +
                           (size_t)M_DIM * sizeof(float));          // N*K int8

    quant_pack<<<M_DIM + 2048, 256, 0, stream>>>(x, w32, qa, ascale, wq);
    gemm_i8<<<1536, 512, 0, stream>>>(qa, wq, ascale, wscale, bias, out);
}

// Round 7
// 503.518 us; speedup vs baseline: 1.1208x; 1.0788x over previous
//
#include <hip/hip_runtime.h>
#include <cstdint>

#define M_DIM 8192
#define K_DIM 4096
#define N_DIM 12288
#define KT 32  // K-tiles of BK=128 int8 (128 B per row)

using i32x4 = __attribute__((ext_vector_type(4))) int;

__device__ inline void gload_lds16(const void* g, void* l) {
    __builtin_amdgcn_global_load_lds(
        (const __attribute__((address_space(1))) void*)g,
        (__attribute__((address_space(3))) void*)l,
        16, 0, 0);
}

// ---------------- fused: per-row quant (blocks 0..M-1) + weight repack ----------------
__global__ __launch_bounds__(256) void quant_pack(const float* __restrict__ x,
                                                  const int* __restrict__ w32,
                                                  int8_t* __restrict__ qa,
                                                  float* __restrict__ ascale,
                                                  int8_t* __restrict__ wq) {
    const int t = threadIdx.x;
    if (blockIdx.x < M_DIM) {
        const int row = blockIdx.x;
        const float4* xr = (const float4*)(x + (size_t)row * K_DIM);
        float4 v[4];
        float amax = 0.0f;
#pragma unroll
        for (int c = 0; c < 4; ++c) {
            v[c] = xr[t + 256 * c];
            amax = fmaxf(amax, fmaxf(fmaxf(fabsf(v[c].x), fabsf(v[c].y)),
                                     fmaxf(fabsf(v[c].z), fabsf(v[c].w))));
        }
#pragma unroll
        for (int off = 32; off > 0; off >>= 1)
            amax = fmaxf(amax, __shfl_xor(amax, off));
        __shared__ float smax[4];
        if ((t & 63) == 0) smax[t >> 6] = amax;
        __syncthreads();
        amax = fmaxf(fmaxf(smax[0], smax[1]), fmaxf(smax[2], smax[3]));
        const float sc = amax * (1.0f / 127.0f);
        const float inv = (amax > 0.0f) ? (127.0f / amax) : 0.0f;
        if (t == 0) ascale[row] = sc;

        int* q32 = (int*)(qa + (size_t)row * K_DIM);
#pragma unroll
        for (int c = 0; c < 4; ++c) {
            int q0 = (int)rintf(v[c].x * inv);
            int q1 = (int)rintf(v[c].y * inv);
            int q2 = (int)rintf(v[c].z * inv);
            int q3 = (int)rintf(v[c].w * inv);
            q0 = min(127, max(-128, q0));
            q1 = min(127, max(-128, q1));
            q2 = min(127, max(-128, q2));
            q3 = min(127, max(-128, q3));
            q32[t + 256 * c] = (q0 & 255) | ((q1 & 255) << 8) | ((q2 & 255) << 16) | (q3 << 24);
        }
    } else {
        const int pb = blockIdx.x - M_DIM;  // 0..2047
        const size_t total4 = (size_t)N_DIM * K_DIM / 4;
        const size_t stride = (size_t)2048 * 256;
        int* out32 = (int*)wq;
        for (size_t i = (size_t)pb * 256 + t; i < total4; i += stride) {
            const int4 v = ((const int4*)w32)[i];
            out32[i] = (v.x & 255) | ((v.y & 255) << 8) | ((v.z & 255) << 16) | (v.w << 24);
        }
    }
}

// ---- int8 GEMM: 256x256 tile, BK=128, dbuf LDS, 4-phase/K-tile fine interleave ----
__global__ __launch_bounds__(512, 2) void gemm_i8(const int8_t* __restrict__ qa,
                                                  const int8_t* __restrict__ wq,
                                                  const float* __restrict__ ascale,
                                                  const float* __restrict__ wscale,
                                                  const float* __restrict__ bias,
                                                  float* __restrict__ out) {
    __shared__ int8_t lds[2][2][32768];  // [slot][A,B][256 rows x 128 B] = 128 KiB

    const int t = threadIdx.x;
    const int lane = t & 63;
    const int wave = t >> 6;       // 0..7
    const int wm = wave >> 2;      // 0..1 -> 128 rows of A
    const int wn = wave & 3;       // 0..3 -> 64 rows of B (cols of C)
    const int lrow = lane & 15;
    const int lk = lane >> 4;      // 0..3 (16B sub-slot within 64B k-slice)
    const int sw7 = lrow & 7;      // read-side XOR swizzle

    // XCD-aware bijective swizzle: 1536 = 8 * 192
    const int flat = blockIdx.x;
    const int sw = (flat & 7) * 192 + (flat >> 3);
    const int bm = sw / 48;  // 0..31
    const int bn = sw % 48;  // 0..47

    // staging: per operand per K-tile = 32 KB = 2048 x 16B slots; thread t covers
    // linear LDS slots {t + 512c, c=0..3} (dest = c*8192 + t*16, strictly linear).
    // row = t>>3 + 64c, sl = t&7; GLOBAL k-slot g = sl ^ (row&7) — same involution
    // the reader applies, so swizzled reads see correct data.
    const int srow = t >> 3;                 // 0..63
    const int g = (t & 7) ^ (srow & 7);      // row&7 invariant under +64c

#define STAGE_OP(ptr, sb, op, rowbase, jt)                                     \
    {                                                                          \
        _Pragma("unroll") for (int c = 0; c < 4; ++c)                          \
            gload_lds16(ptr + (size_t)((rowbase) + srow + 64 * c) * K_DIM +    \
                            (size_t)g * 16 + (size_t)(jt) * 128,               \
                        &lds[sb][op][c * 8192 + t * 16]);                      \
    }

    // fragment reads: A row r = wm*128 + mh*64 + mf*16 + lrow; global k-slot
    // s = ks*4+lk lives at LDS slot s ^ (lrow&7).
#define READ_A(dst, LA, mh)                                                    \
    {                                                                          \
        _Pragma("unroll") for (int mf = 0; mf < 4; ++mf)                       \
            _Pragma("unroll") for (int ks = 0; ks < 2; ++ks)                   \
                dst[mf][ks] = *(const i32x4*)&LA[(wm * 128 + (mh)*64 +         \
                                                 mf * 16 + lrow) * 128 +       \
                                                ((((ks << 2) | lk) ^ sw7) << 4)]; \
    }
#define READ_B(dst, LB, nh)                                                    \
    {                                                                          \
        _Pragma("unroll") for (int nf = 0; nf < 2; ++nf)                       \
            _Pragma("unroll") for (int ks = 0; ks < 2; ++ks)                   \
                dst[nf][ks] = *(const i32x4*)&LB[(wn * 64 + (nh)*32 +          \
                                                 nf * 16 + lrow) * 128 +       \
                                                ((((ks << 2) | lk) ^ sw7) << 4)]; \
    }
    // 16-MFMA cluster for quadrant (mh, nh); ks outer for dep distance
#define MM(AH, BH, mh, nh)                                                     \
    {                                                                          \
        __builtin_amdgcn_s_setprio(1);                                         \
        _Pragma("unroll") for (int ks = 0; ks < 2; ++ks)                       \
            _Pragma("unroll") for (int mf = 0; mf < 4; ++mf)                   \
                _Pragma("unroll") for (int nf = 0; nf < 2; ++nf)               \
                    acc[(mh)*4 + mf][(nh)*2 + nf] =                            \
                        __builtin_amdgcn_mfma_i32_16x16x64_i8(                 \
                            AH[mf][ks], BH[nf][ks],                            \
                            acc[(mh)*4 + mf][(nh)*2 + nf], 0, 0, 0);           \
        __builtin_amdgcn_s_setprio(0);                                         \
    }
#define LGKM0_PIN                                                              \
    asm volatile("s_waitcnt lgkmcnt(0)" ::: "memory");                         \
    __builtin_amdgcn_sched_barrier(0);

    i32x4 acc[8][4] = {};
    i32x4 a0[4][2], a1[4][2], b0[2][2], b1[2][2];

    // prologue: stage tile 0 fully (8 loads/thread outstanding)
    STAGE_OP(qa, 0, 0, bm * 256, 0);
    STAGE_OP(wq, 0, 1, bn * 256, 0);

    for (int j = 0; j < KT; ++j) {
        const int cs = j & 1;
        const int ns = cs ^ 1;
        const int8_t* __restrict__ LA = lds[cs][0];
        const int8_t* __restrict__ LB = lds[cs][1];

        // ---- phase 0: stage A(j+1) | counted wait | barrier | read a0,b0 | MM(0,0)
        if (j + 1 < KT) {
            STAGE_OP(qa, ns, 0, bm * 256, j + 1);
            asm volatile("s_waitcnt vmcnt(4)" ::: "memory");  // tile j landed
        } else {
            asm volatile("s_waitcnt vmcnt(0)" ::: "memory");
        }
        __builtin_amdgcn_s_barrier();
        __builtin_amdgcn_sched_barrier(0);
        READ_A(a0, LA, 0);
        READ_B(b0, LB, 0);
        LGKM0_PIN;
        MM(a0, b0, 0, 0);

        // ---- phase 1: read b1 | stage B(j+1) | barrier | MM(0,1)
        READ_B(b1, LB, 1);
        if (j + 1 < KT) STAGE_OP(wq, ns, 1, bn * 256, j + 1);
        __builtin_amdgcn_s_barrier();
        LGKM0_PIN;
        MM(a0, b1, 0, 1);

        // ---- phase 2: read a1 | barrier | MM(1,1)
        READ_A(a1, LA, 1);
        __builtin_amdgcn_s_barrier();
        LGKM0_PIN;
        MM(a1, b1, 1, 1);

        // ---- phase 3: barrier | MM(1,0)  (b0, a1 already in regs)
        __builtin_amdgcn_s_barrier();
        __builtin_amdgcn_sched_barrier(0);
        MM(a1, b0, 1, 0);
    }

    // epilogue: C/D layout col = lane&15, row = (lane>>4)*4 + j
    const int r0 = bm * 256 + wm * 128;
    const int c0 = bn * 256 + wn * 64;
    float asc[8][4];
#pragma unroll
    for (int m = 0; m < 8; ++m)
#pragma unroll
        for (int jj = 0; jj < 4; ++jj)
            asc[m][jj] = ascale[r0 + m * 16 + lk * 4 + jj];
#pragma unroll
    for (int n = 0; n < 4; ++n) {
        const int col = c0 + n * 16 + lrow;
        const float wsc = wscale[col];
        const float bb = bias[col];
#pragma unroll
        for (int m = 0; m < 8; ++m) {
#pragma unroll
            for (int jj = 0; jj < 4; ++jj) {
                const int row = r0 + m * 16 + lk * 4 + jj;
                out[(size_t)row * N_DIM + col] = (float)acc[m][n][jj] * asc[m][jj] * wsc + bb;
            }
        }
    }
}

extern "C" void kernel_launch(void* const* d_in, const int* in_sizes, int n_in,
                              void* d_out, int out_size, void* d_ws, size_t ws_size,
                              hipStream_t stream) {
    const float* x = (const float*)d_in[0];
    const int* w32 = (const int*)d_in[1];  // int8 weights arrive as int32
    const float* wscale = (const float*)d_in[2];
    const float* bias = (const float*)d_in[3];
    float* out = (float*)d_out;

    int8_t* qa = (int8_t*)d_ws;                                     // M*K int8
    float* ascale = (float*)((char*)d_ws + (size_t)M_DIM * K_DIM);  // M f32
    int8_t* wq = (int8_t*)((char*)d_ws + (size_t)M_DIM * K_DIM +
                           (size_t)M_DIM * sizeof(float));          // N*K int8

    quant_pack<<<M_DIM + 2048, 256, 0, stream>>>(x, w32, qa, ascale, wq);
    gemm_i8<<<1536, 512, 0, stream>>>(qa, wq, ascale, wscale, bias, out);
}